// Round 1
// baseline (295.502 us; speedup 1.0000x reference)
//
#include <hip/hip_runtime.h>

#define SEQ   2048
#define NH    32
#define NKV   8
#define HD    128
#define GROUP (NH / NKV)
#define QBLK  64
#define KVBLK 64
#define SCALE 0.08838834764831845f

#define QSTRIDE  (NH * HD)    // 4096 floats
#define KVSTRIDE (NKV * HD)   // 1024 floats

#define KPAD 136   // K_lds row length (bf16 elems): 272B, 16B-aligned, 2-way-free banks
#define VPAD 72    // Vt_lds row length: 144B, 16B-aligned, 2-way-free banks
#define PPAD 72    // P_lds row length

typedef __attribute__((ext_vector_type(8))) __bf16 bf16x8;
typedef __attribute__((ext_vector_type(4))) __bf16 bf16x4;
typedef __attribute__((ext_vector_type(2))) __bf16 bf16x2;
typedef __attribute__((ext_vector_type(4))) float  f32x4;

__global__ __launch_bounds__(256, 3)
void fa_fwd_kernel(const float* __restrict__ Q, const float* __restrict__ K,
                   const float* __restrict__ V, float* __restrict__ O) {
    __shared__ __bf16 Klds[KVBLK][KPAD];   // K tile, row-major [k][d]
    __shared__ __bf16 Vt[HD][VPAD];        // V tile, transposed [d][k]
    __shared__ __bf16 Plds[4][16][PPAD];   // per-wave P tile [q][k]

    const int h    = blockIdx.y;                       // query head
    const int qb   = gridDim.x - 1 - blockIdx.x;       // heavy blocks dispatch first
    const int hkv  = h >> 2;                           // kv head (GROUP=4)
    const int tid  = threadIdx.x;
    const int wave = tid >> 6;
    const int lane = tid & 63;
    const int lmod = lane & 15;
    const int lhi  = lane >> 4;                        // 0..3

    const int q0 = qb * QBLK;

    // ---- Load Q fragments once (scaled, bf16). A-frag: [q=lmod][k=lhi*8+j] ----
    bf16x8 qfrag[4];
    {
        const float* qp = Q + (size_t)(q0 + wave * 16 + lmod) * QSTRIDE + h * HD;
#pragma unroll
        for (int ks = 0; ks < 4; ++ks) {
            float4 a = *(const float4*)(qp + ks * 32 + lhi * 8);
            float4 b = *(const float4*)(qp + ks * 32 + lhi * 8 + 4);
            bf16x8 f;
            f[0] = (__bf16)(a.x * SCALE); f[1] = (__bf16)(a.y * SCALE);
            f[2] = (__bf16)(a.z * SCALE); f[3] = (__bf16)(a.w * SCALE);
            f[4] = (__bf16)(b.x * SCALE); f[5] = (__bf16)(b.y * SCALE);
            f[6] = (__bf16)(b.z * SCALE); f[7] = (__bf16)(b.w * SCALE);
            qfrag[ks] = f;
        }
    }

    f32x4 acc[8];
#pragma unroll
    for (int d = 0; d < 8; ++d) acc[d] = (f32x4){0.f, 0.f, 0.f, 0.f};
    float rmax[4] = {-1e30f, -1e30f, -1e30f, -1e30f};
    float rsum[4] = {0.f, 0.f, 0.f, 0.f};

    const int ntiles = qb + 1;
    for (int t = 0; t < ntiles; ++t) {
        const int kv0 = t * KVBLK;
        __syncthreads();   // protect LDS from previous iteration's readers

        // ---- Stage K tile: fp32 -> bf16, row-major, coalesced ----
#pragma unroll
        for (int i = 0; i < 8; ++i) {
            int lin = i * 1024 + tid * 4;
            int row = lin >> 7, col = lin & 127;
            float4 kvv = *(const float4*)(K + (size_t)(kv0 + row) * KVSTRIDE + hkv * HD + col);
            bf16x4 w = {(__bf16)kvv.x, (__bf16)kvv.y, (__bf16)kvv.z, (__bf16)kvv.w};
            *(bf16x4*)&Klds[row][col] = w;
        }
        // ---- Stage V tile transposed: Vt[d][k] ----
        {
            int p = tid >> 3;    // k-pair: rows 2p, 2p+1
            int g = tid & 7;     // d-group: d = g*16 .. +15
            const float* v0p = V + (size_t)(kv0 + 2 * p) * KVSTRIDE + hkv * HD + g * 16;
            const float* v1p = v0p + KVSTRIDE;
#pragma unroll
            for (int i = 0; i < 4; ++i) {
                float4 a = *(const float4*)(v0p + i * 4);
                float4 b = *(const float4*)(v1p + i * 4);
                int d = g * 16 + i * 4;
                *(bf16x2*)&Vt[d + 0][2 * p] = (bf16x2){(__bf16)a.x, (__bf16)b.x};
                *(bf16x2*)&Vt[d + 1][2 * p] = (bf16x2){(__bf16)a.y, (__bf16)b.y};
                *(bf16x2*)&Vt[d + 2][2 * p] = (bf16x2){(__bf16)a.z, (__bf16)b.z};
                *(bf16x2*)&Vt[d + 3][2 * p] = (bf16x2){(__bf16)a.w, (__bf16)b.w};
            }
        }
        __syncthreads();   // staging visible

        // ---- QK^T: 16x64 scores per wave ----
        f32x4 s[4];
#pragma unroll
        for (int ct = 0; ct < 4; ++ct) {
            f32x4 c = (f32x4){0.f, 0.f, 0.f, 0.f};
#pragma unroll
            for (int ks = 0; ks < 4; ++ks) {
                bf16x8 bfrag = *(const bf16x8*)&Klds[ct * 16 + lmod][ks * 32 + lhi * 8];
                c = __builtin_amdgcn_mfma_f32_16x16x32_bf16(qfrag[ks], bfrag, c, 0, 0, 0);
            }
            s[ct] = c;
        }

        // ---- Causal mask (diagonal tile only) ----
        if (kv0 + KVBLK - 1 > q0) {
#pragma unroll
            for (int ct = 0; ct < 4; ++ct) {
                int colg = kv0 + ct * 16 + lmod;
#pragma unroll
                for (int r = 0; r < 4; ++r) {
                    int rowg = q0 + wave * 16 + lhi * 4 + r;
                    if (colg > rowg) s[ct][r] = -1e30f;
                }
            }
        }

        // ---- Online softmax (row r lives on 16 lanes sharing lhi) ----
#pragma unroll
        for (int r = 0; r < 4; ++r) {
            float tmax = fmaxf(fmaxf(s[0][r], s[1][r]), fmaxf(s[2][r], s[3][r]));
#pragma unroll
            for (int m = 1; m < 16; m <<= 1) tmax = fmaxf(tmax, __shfl_xor(tmax, m));
            float mnew = fmaxf(rmax[r], tmax);
            float corr = __expf(rmax[r] - mnew);
            float p0 = __expf(s[0][r] - mnew);
            float p1 = __expf(s[1][r] - mnew);
            float p2 = __expf(s[2][r] - mnew);
            float p3 = __expf(s[3][r] - mnew);
            float psum = (p0 + p1) + (p2 + p3);
#pragma unroll
            for (int m = 1; m < 16; m <<= 1) psum += __shfl_xor(psum, m);
            rsum[r] = rsum[r] * corr + psum;
            rmax[r] = mnew;
#pragma unroll
            for (int d = 0; d < 8; ++d) acc[d][r] *= corr;
            int prow = lhi * 4 + r;
            Plds[wave][prow][0 * 16 + lmod] = (__bf16)p0;
            Plds[wave][prow][1 * 16 + lmod] = (__bf16)p1;
            Plds[wave][prow][2 * 16 + lmod] = (__bf16)p2;
            Plds[wave][prow][3 * 16 + lmod] = (__bf16)p3;
        }
        __syncthreads();   // P visible (also orders same-wave ds_write -> ds_read)

        // ---- PV: acc[16 q][128 d] += P[16x64] * V[64x128] ----
        bf16x8 pa[2];
#pragma unroll
        for (int ks2 = 0; ks2 < 2; ++ks2)
            pa[ks2] = *(const bf16x8*)&Plds[wave][lmod][ks2 * 32 + lhi * 8];
#pragma unroll
        for (int dt = 0; dt < 8; ++dt) {
            f32x4 c = acc[dt];
#pragma unroll
            for (int ks2 = 0; ks2 < 2; ++ks2) {
                bf16x8 bfrag = *(const bf16x8*)&Vt[dt * 16 + lmod][ks2 * 32 + lhi * 8];
                c = __builtin_amdgcn_mfma_f32_16x16x32_bf16(pa[ks2], bfrag, c, 0, 0, 0);
            }
            acc[dt] = c;
        }
    }

    // ---- Epilogue: O = acc / rsum ----
    float inv[4];
#pragma unroll
    for (int r = 0; r < 4; ++r) inv[r] = 1.0f / rsum[r];
#pragma unroll
    for (int dt = 0; dt < 8; ++dt) {
#pragma unroll
        for (int r = 0; r < 4; ++r) {
            int rowg = q0 + wave * 16 + lhi * 4 + r;
            O[(size_t)rowg * QSTRIDE + h * HD + dt * 16 + lmod] = acc[dt][r] * inv[r];
        }
    }
}

extern "C" void kernel_launch(void* const* d_in, const int* in_sizes, int n_in,
                              void* d_out, int out_size, void* d_ws, size_t ws_size,
                              hipStream_t stream) {
    const float* Q = (const float*)d_in[0];
    const float* K = (const float*)d_in[1];
    const float* V = (const float*)d_in[2];
    float* O = (float*)d_out;
    dim3 grid(SEQ / QBLK, NH);
    fa_fwd_kernel<<<grid, dim3(256), 0, stream>>>(Q, K, V, O);
}

// Round 4
// 261.896 us; speedup vs baseline: 1.1283x; 1.1283x over previous
//
#include <hip/hip_runtime.h>

#define SEQ   2048
#define NH    32
#define NKV   8
#define HD    128
#define QBLK  64
#define KVBLK 64
#define SCALE 0.08838834764831845f
#define QSTRIDE  4096
#define KVSTRIDE 1024
#define KPAD 136  // K rows: 128 bf16 data + 8 pad = 272B (17 granules) -> balanced b128 reads

typedef __attribute__((ext_vector_type(8))) __bf16 bf16x8;
typedef __attribute__((ext_vector_type(4))) __bf16 bf16x4;
typedef __attribute__((ext_vector_type(4))) float  f32x4;

__device__ __forceinline__ unsigned pkbf(float a, float b) {
    union { __bf16 h[2]; unsigned u; } w;
    w.h[0] = (__bf16)a; w.h[1] = (__bf16)b;
    return w.u;
}

// Vt element offset: d-major rows of 64 bf16 (128B), 16B-granule XOR swizzle by (d>>2)&7.
// Writes (b64, d varies by lane) and reads (b128, k varies by lane) both conflict-free/2-way.
__device__ __forceinline__ int vt_elem(int d, int g) { // g = 16B granule index 0..7 (pre-XOR)
    return d * 64 + ((g ^ ((d >> 2) & 7)) << 3);
}

__global__ __launch_bounds__(256, 2)
void fa_fwd_kernel(const float* __restrict__ Q, const float* __restrict__ K,
                   const float* __restrict__ V, float* __restrict__ O) {
    __shared__ __bf16 Klds[KVBLK][KPAD];   // [k][d]
    __shared__ __bf16 Vt[HD * 64];         // [d][k] swizzled

    const int h    = blockIdx.y;
    const int qb   = gridDim.x - 1 - blockIdx.x;   // heavy blocks first
    const int hkv  = h >> 2;
    const int tid  = threadIdx.x;
    const int wave = tid >> 6;
    const int lane = tid & 63;
    const int lmod = lane & 15;
    const int lhi  = lane >> 4;
    const int q0   = qb * QBLK;

    // ---- Q fragments (scaled, bf16): B-frag for swapped QK^T ----
    bf16x8 qfrag[4];
    {
        const float* qp = Q + (size_t)(q0 + wave * 16 + lmod) * QSTRIDE + h * HD;
#pragma unroll
        for (int ks = 0; ks < 4; ++ks) {
            f32x4 a = *(const f32x4*)(qp + ks * 32 + lhi * 8);
            f32x4 b = *(const f32x4*)(qp + ks * 32 + lhi * 8 + 4);
            bf16x8 f;
            f[0] = (__bf16)(a[0] * SCALE); f[1] = (__bf16)(a[1] * SCALE);
            f[2] = (__bf16)(a[2] * SCALE); f[3] = (__bf16)(a[3] * SCALE);
            f[4] = (__bf16)(b[0] * SCALE); f[5] = (__bf16)(b[1] * SCALE);
            f[6] = (__bf16)(b[2] * SCALE); f[7] = (__bf16)(b[3] * SCALE);
            qfrag[ks] = f;
        }
    }

    // ---- staging registers (prefetch in flight across compute) ----
    f32x4 kr[8];        // K: 8 rows x float4
    f32x4 vr[2][4];     // V: 2 k-groups x 4 rows x float4
    const int dq    = tid & 31;       // V: d-quad 0..31 (coalesced)
    const int kg2   = tid >> 5;       // V: k-group base 0..7
    const int krow  = tid >> 5;       // K: row-within-8 0..7
    const int kcol  = (tid & 31) * 4; // K: d column

    auto LOAD_KV = [&](int kv0) {
        const float* kp = K + (size_t)kv0 * KVSTRIDE + hkv * HD + kcol;
#pragma unroll
        for (int i = 0; i < 8; ++i)
            kr[i] = *(const f32x4*)(kp + (size_t)(i * 8 + krow) * KVSTRIDE);
#pragma unroll
        for (int it = 0; it < 2; ++it) {
            const int kg = kg2 + it * 8;
            const float* vp = V + (size_t)(kv0 + kg * 4) * KVSTRIDE + hkv * HD + dq * 4;
#pragma unroll
            for (int rr = 0; rr < 4; ++rr)
                vr[it][rr] = *(const f32x4*)(vp + rr * KVSTRIDE);
        }
    };

    auto WRITE_KV = [&]() {
#pragma unroll
        for (int i = 0; i < 8; ++i) {
            bf16x4 w = {(__bf16)kr[i][0], (__bf16)kr[i][1], (__bf16)kr[i][2], (__bf16)kr[i][3]};
            *(bf16x4*)&Klds[i * 8 + krow][kcol] = w;
        }
#pragma unroll
        for (int it = 0; it < 2; ++it) {
            const int kg = kg2 + it * 8;
#pragma unroll
            for (int c = 0; c < 4; ++c) {
                const int d = dq * 4 + c;
                bf16x4 w = {(__bf16)vr[it][0][c], (__bf16)vr[it][1][c],
                            (__bf16)vr[it][2][c], (__bf16)vr[it][3][c]};
                *(bf16x4*)&Vt[vt_elem(d, kg >> 1) + (kg & 1) * 4] = w;
            }
        }
    };

    f32x4 acc[8];   // O^T: acc[dt][r] = O[q=lmod][d = dt*16 + lhi*4 + r]
#pragma unroll
    for (int d = 0; d < 8; ++d) acc[d] = (f32x4){0.f, 0.f, 0.f, 0.f};
    float rmax = -1e30f, rsum = 0.f;   // per-lane state for q = lmod (replicated over lhi)

    LOAD_KV(0);
    WRITE_KV();

    const int nt = qb + 1;
    for (int t = 0; t < nt; ++t) {
        __syncthreads();                       // tile t staged & prior reads done
        const bool pf = (t + 1 < nt);
        if (pf) LOAD_KV((t + 1) * KVBLK);      // fire next tile's loads (hidden under compute)

        // ---- swapped QK^T: S^T[k][q], lane holds k = ct*16 + lhi*4 + r, q = lmod ----
        f32x4 s[4];
#pragma unroll
        for (int ct = 0; ct < 4; ++ct) {
            f32x4 c = (f32x4){0.f, 0.f, 0.f, 0.f};
#pragma unroll
            for (int ks = 0; ks < 4; ++ks) {
                bf16x8 kf = *(const bf16x8*)&Klds[ct * 16 + lmod][ks * 32 + lhi * 8];
                c = __builtin_amdgcn_mfma_f32_16x16x32_bf16(kf, qfrag[ks], c, 0, 0, 0);
            }
            s[ct] = c;
        }

        if (t == nt - 1) {                     // causal mask (diagonal tile only)
            const int kv0 = t * KVBLK;
            const int qg  = q0 + wave * 16 + lmod;
#pragma unroll
            for (int ct = 0; ct < 4; ++ct)
#pragma unroll
                for (int r = 0; r < 4; ++r)
                    if (kv0 + ct * 16 + lhi * 4 + r > qg) s[ct][r] = -1e30f;
        }

        // ---- lane-local online softmax ----
        float tmax = s[0][0];
#pragma unroll
        for (int ct = 0; ct < 4; ++ct)
#pragma unroll
            for (int r = 0; r < 4; ++r) tmax = fmaxf(tmax, s[ct][r]);
        tmax = fmaxf(tmax, __shfl_xor(tmax, 16));
        tmax = fmaxf(tmax, __shfl_xor(tmax, 32));
        const float mnew = fmaxf(rmax, tmax);
        const float corr = __expf(rmax - mnew);
        float psum = 0.f;
#pragma unroll
        for (int ct = 0; ct < 4; ++ct)
#pragma unroll
            for (int r = 0; r < 4; ++r) {
                s[ct][r] = __expf(s[ct][r] - mnew);
                psum += s[ct][r];
            }
        psum += __shfl_xor(psum, 16);
        psum += __shfl_xor(psum, 32);
        rsum = rsum * corr + psum;
        rmax = mnew;
#pragma unroll
        for (int d = 0; d < 8; ++d) acc[d] *= corr;

        // ---- pack P to bf16 + cross-lane redistribute into PV B-fragments ----
        unsigned pk[4][2];
#pragma unroll
        for (int ct = 0; ct < 4; ++ct) {
            pk[ct][0] = pkbf(s[ct][0], s[ct][1]);
            pk[ct][1] = pkbf(s[ct][2], s[ct][3]);
        }
        const int  sA    = lmod + ((lhi & 1) << 5);
        const int  sB    = sA + 16;
        const bool selhi = (lhi >> 1) != 0;
        bf16x8 pfrag[2];
#pragma unroll
        for (int ks2 = 0; ks2 < 2; ++ks2) {
            const int ctA = ks2 * 2, ctB = ks2 * 2 + 1;
            unsigned d0a = __shfl((int)pk[ctA][0], sA), d0b = __shfl((int)pk[ctB][0], sA);
            unsigned d1a = __shfl((int)pk[ctA][1], sA), d1b = __shfl((int)pk[ctB][1], sA);
            unsigned d2a = __shfl((int)pk[ctA][0], sB), d2b = __shfl((int)pk[ctB][0], sB);
            unsigned d3a = __shfl((int)pk[ctA][1], sB), d3b = __shfl((int)pk[ctB][1], sB);
            union { unsigned u[4]; bf16x8 v; } fb;
            fb.u[0] = selhi ? d0b : d0a;
            fb.u[1] = selhi ? d1b : d1a;
            fb.u[2] = selhi ? d2b : d2a;
            fb.u[3] = selhi ? d3b : d3a;
            pfrag[ks2] = fb.v;
        }

        // ---- swapped PV: O^T += V^T * P^T ----
#pragma unroll
        for (int dt = 0; dt < 8; ++dt) {
            f32x4 c = acc[dt];
#pragma unroll
            for (int ks2 = 0; ks2 < 2; ++ks2) {
                const int d = dt * 16 + lmod;
                bf16x8 vf = *(const bf16x8*)&Vt[vt_elem(d, ks2 * 4 + lhi)];
                c = __builtin_amdgcn_mfma_f32_16x16x32_bf16(vf, pfrag[ks2], c, 0, 0, 0);
            }
            acc[dt] = c;
        }

        __syncthreads();                       // all reads of tile t done
        if (pf) WRITE_KV();                    // stage tile t+1 (vmcnt waits here, hidden)
    }

    // ---- epilogue: O = O^T/rsum, float4 stores ----
    const float inv = 1.0f / rsum;
    const int qg = q0 + wave * 16 + lmod;
    float* op = O + (size_t)qg * QSTRIDE + h * HD + lhi * 4;
#pragma unroll
    for (int dt = 0; dt < 8; ++dt) {
        f32x4 o = acc[dt] * inv;
        *(f32x4*)(op + dt * 16) = o;
    }
}

extern "C" void kernel_launch(void* const* d_in, const int* in_sizes, int n_in,
                              void* d_out, int out_size, void* d_ws, size_t ws_size,
                              hipStream_t stream) {
    const float* Q = (const float*)d_in[0];
    const float* K = (const float*)d_in[1];
    const float* V = (const float*)d_in[2];
    float* O = (float*)d_out;
    dim3 grid(SEQ / QBLK, NH);
    fa_fwd_kernel<<<grid, dim3(256), 0, stream>>>(Q, K, V, O);
}

// Round 5
// 243.839 us; speedup vs baseline: 1.2119x; 1.0741x over previous
//
#include <hip/hip_runtime.h>

#define SEQ   2048
#define NH    32
#define NKV   8
#define HD    128
#define QBLK  64
#define KVBLK 64
#define SCALE 0.08838834764831845f
#define QSTRIDE  4096
#define KVSTRIDE 1024
#define KPAD 136  // K rows: 128 bf16 data + 8 pad = 272B -> b128 reads & b64 writes at bank floor

typedef __attribute__((ext_vector_type(8))) __bf16 bf16x8;
typedef __attribute__((ext_vector_type(4))) __bf16 bf16x4;
typedef __attribute__((ext_vector_type(4))) float  f32x4;

__device__ __forceinline__ unsigned pkbf(float a, float b) {
    union { __bf16 h[2]; unsigned u; } w;
    w.h[0] = (__bf16)a; w.h[1] = (__bf16)b;
    return w.u;
}

// Vt layout: [d][64 k] bf16 rows (128B), swizzled in 8B slots: slot ^= (d ^ (d>>2)) & 15.
// GF(2)-checked: PV b64 reads (d low bits vary per lane) AND transpose b64 writes
// (d high bits vary per lane) both land exactly on the 4-lane/slot bank floor.
__device__ __forceinline__ int vt_swz(int d) { return (d ^ (d >> 2)) & 15; }

__global__ __launch_bounds__(256, 2)
void fa_fwd_kernel(const float* __restrict__ Q, const float* __restrict__ K,
                   const float* __restrict__ V, float* __restrict__ O) {
    __shared__ __bf16 Klds[KVBLK][KPAD];   // [k][d]
    __shared__ __bf16 Vt[HD * 64];         // [d][k], 8B-slot swizzled

    const int h    = blockIdx.y;
    const int qb   = gridDim.x - 1 - blockIdx.x;   // heavy blocks first
    const int hkv  = h >> 2;
    const int tid  = threadIdx.x;
    const int wave = tid >> 6;
    const int lane = tid & 63;
    const int lmod = lane & 15;
    const int lhi  = lane >> 4;
    const int q0   = qb * QBLK;

    // ---- Q fragments (scaled, bf16): B-frag for swapped QK^T ----
    bf16x8 qfrag[4];
    {
        const float* qp = Q + (size_t)(q0 + wave * 16 + lmod) * QSTRIDE + h * HD;
#pragma unroll
        for (int ks = 0; ks < 4; ++ks) {
            f32x4 a = *(const f32x4*)(qp + ks * 32 + lhi * 8);
            f32x4 b = *(const f32x4*)(qp + ks * 32 + lhi * 8 + 4);
            bf16x8 f;
            f[0] = (__bf16)(a[0] * SCALE); f[1] = (__bf16)(a[1] * SCALE);
            f[2] = (__bf16)(a[2] * SCALE); f[3] = (__bf16)(a[3] * SCALE);
            f[4] = (__bf16)(b[0] * SCALE); f[5] = (__bf16)(b[1] * SCALE);
            f[6] = (__bf16)(b[2] * SCALE); f[7] = (__bf16)(b[3] * SCALE);
            qfrag[ks] = f;
        }
    }

    // ---- staging registers (prefetch in flight across compute) ----
    f32x4 kr[8];        // K: 8 rows x float4
    f32x4 vr[2][4];     // V: 2 k-groups x 4 rows x float4
    const int dq    = tid & 31;       // V: d-quad 0..31 (coalesced)
    const int kg2   = tid >> 5;       // V: k-group base 0..7
    const int krow  = tid >> 5;       // K: row-within-8 0..7
    const int kcol  = (tid & 31) * 4; // K: d column

    auto LOAD_KV = [&](int kv0) {
        const float* kp = K + (size_t)kv0 * KVSTRIDE + hkv * HD + kcol;
#pragma unroll
        for (int i = 0; i < 8; ++i)
            kr[i] = *(const f32x4*)(kp + (size_t)(i * 8 + krow) * KVSTRIDE);
#pragma unroll
        for (int it = 0; it < 2; ++it) {
            const int kg = kg2 + it * 8;
            const float* vp = V + (size_t)(kv0 + kg * 4) * KVSTRIDE + hkv * HD + dq * 4;
#pragma unroll
            for (int rr = 0; rr < 4; ++rr)
                vr[it][rr] = *(const f32x4*)(vp + rr * KVSTRIDE);
        }
    };

    auto WRITE_KV = [&]() {
#pragma unroll
        for (int i = 0; i < 8; ++i) {
            bf16x4 w = {(__bf16)kr[i][0], (__bf16)kr[i][1], (__bf16)kr[i][2], (__bf16)kr[i][3]};
            *(bf16x4*)&Klds[i * 8 + krow][kcol] = w;
        }
#pragma unroll
        for (int it = 0; it < 2; ++it) {
            const int kg = kg2 + it * 8;
#pragma unroll
            for (int c = 0; c < 4; ++c) {
                const int d = dq * 4 + c;
                bf16x4 w = {(__bf16)vr[it][0][c], (__bf16)vr[it][1][c],
                            (__bf16)vr[it][2][c], (__bf16)vr[it][3][c]};
                *(bf16x4*)&Vt[d * 64 + ((kg ^ vt_swz(d)) << 2)] = w;
            }
        }
    };

    f32x4 acc[8];   // O^T: acc[dt][r] = O[q=lmod][d = dt*16 + lhi*4 + r]
#pragma unroll
    for (int d = 0; d < 8; ++d) acc[d] = (f32x4){0.f, 0.f, 0.f, 0.f};
    float rmax = -1e30f, rsum = 0.f;   // per-lane state for q = lmod (replicated over lhi)

    LOAD_KV(0);
    WRITE_KV();

    const int nt = qb + 1;
    for (int t = 0; t < nt; ++t) {
        __syncthreads();                       // tile t staged & prior reads done
        const bool pf = (t + 1 < nt);
        if (pf) LOAD_KV((t + 1) * KVBLK);      // fire next tile's loads (hidden under compute)

        // ---- swapped QK^T: S^T[k][q], lane holds k = ct*16 + lhi*4 + r, q = lmod ----
        f32x4 s[4];
        __builtin_amdgcn_s_setprio(1);
#pragma unroll
        for (int ct = 0; ct < 4; ++ct) {
            f32x4 c = (f32x4){0.f, 0.f, 0.f, 0.f};
#pragma unroll
            for (int ks = 0; ks < 4; ++ks) {
                bf16x8 kf = *(const bf16x8*)&Klds[ct * 16 + lmod][ks * 32 + lhi * 8];
                c = __builtin_amdgcn_mfma_f32_16x16x32_bf16(kf, qfrag[ks], c, 0, 0, 0);
            }
            s[ct] = c;
        }
        __builtin_amdgcn_s_setprio(0);

        if (t == nt - 1) {                     // causal mask (diagonal tile only)
            const int kv0 = t * KVBLK;
            const int qg  = q0 + wave * 16 + lmod;
#pragma unroll
            for (int ct = 0; ct < 4; ++ct)
#pragma unroll
                for (int r = 0; r < 4; ++r)
                    if (kv0 + ct * 16 + lhi * 4 + r > qg) s[ct][r] = -1e30f;
        }

        // ---- lane-local online softmax ----
        float tmax = s[0][0];
#pragma unroll
        for (int ct = 0; ct < 4; ++ct)
#pragma unroll
            for (int r = 0; r < 4; ++r) tmax = fmaxf(tmax, s[ct][r]);
        tmax = fmaxf(tmax, __shfl_xor(tmax, 16));
        tmax = fmaxf(tmax, __shfl_xor(tmax, 32));
        const float mnew = fmaxf(rmax, tmax);
        const float corr = __expf(rmax - mnew);
        float psum = 0.f;
#pragma unroll
        for (int ct = 0; ct < 4; ++ct)
#pragma unroll
            for (int r = 0; r < 4; ++r) {
                s[ct][r] = __expf(s[ct][r] - mnew);
                psum += s[ct][r];
            }
        psum += __shfl_xor(psum, 16);
        psum += __shfl_xor(psum, 32);
        rsum = rsum * corr + psum;
        rmax = mnew;
#pragma unroll
        for (int d = 0; d < 8; ++d) acc[d] *= corr;

        // ---- pack P to bf16 + cross-lane redistribute into PV B-fragments ----
        unsigned pk[4][2];
#pragma unroll
        for (int ct = 0; ct < 4; ++ct) {
            pk[ct][0] = pkbf(s[ct][0], s[ct][1]);
            pk[ct][1] = pkbf(s[ct][2], s[ct][3]);
        }
        const int  sA    = lmod + ((lhi & 1) << 5);
        const int  sB    = sA + 16;
        const bool selhi = (lhi >> 1) != 0;
        bf16x8 pfrag[2];
#pragma unroll
        for (int ks2 = 0; ks2 < 2; ++ks2) {
            const int ctA = ks2 * 2, ctB = ks2 * 2 + 1;
            unsigned d0a = __shfl((int)pk[ctA][0], sA), d0b = __shfl((int)pk[ctB][0], sA);
            unsigned d1a = __shfl((int)pk[ctA][1], sA), d1b = __shfl((int)pk[ctB][1], sA);
            unsigned d2a = __shfl((int)pk[ctA][0], sB), d2b = __shfl((int)pk[ctB][0], sB);
            unsigned d3a = __shfl((int)pk[ctA][1], sB), d3b = __shfl((int)pk[ctB][1], sB);
            union { unsigned u[4]; bf16x8 v; } fb;
            fb.u[0] = selhi ? d0b : d0a;
            fb.u[1] = selhi ? d1b : d1a;
            fb.u[2] = selhi ? d2b : d2a;
            fb.u[3] = selhi ? d3b : d3a;
            pfrag[ks2] = fb.v;
        }

        // ---- swapped PV: O^T += V^T * P^T  (2x b64 swizzled reads per fragment) ----
        __builtin_amdgcn_s_setprio(1);
#pragma unroll
        for (int dt = 0; dt < 8; ++dt) {
            const int d    = dt * 16 + lmod;
            const int rb   = d * 64;
            const int swzd = vt_swz(d);
            f32x4 c = acc[dt];
#pragma unroll
            for (int ks2 = 0; ks2 < 2; ++ks2) {
                union { bf16x4 h4[2]; bf16x8 v8; } vf;
#pragma unroll
                for (int hh = 0; hh < 2; ++hh) {
                    const int slot = ((ks2 << 3) | (lhi << 1) | hh) ^ swzd;
                    vf.h4[hh] = *(const bf16x4*)&Vt[rb + slot * 4];
                }
                c = __builtin_amdgcn_mfma_f32_16x16x32_bf16(vf.v8, pfrag[ks2], c, 0, 0, 0);
            }
            acc[dt] = c;
        }
        __builtin_amdgcn_s_setprio(0);

        __syncthreads();                       // all reads of tile t done
        if (pf) WRITE_KV();                    // stage tile t+1 (vmcnt waits here, hidden)
    }

    // ---- epilogue: O = O^T/rsum, float4 stores ----
    const float inv = 1.0f / rsum;
    const int qg = q0 + wave * 16 + lmod;
    float* op = O + (size_t)qg * QSTRIDE + h * HD + lhi * 4;
#pragma unroll
    for (int dt = 0; dt < 8; ++dt) {
        f32x4 o = acc[dt] * inv;
        *(f32x4*)(op + dt * 16) = o;
    }
}

extern "C" void kernel_launch(void* const* d_in, const int* in_sizes, int n_in,
                              void* d_out, int out_size, void* d_ws, size_t ws_size,
                              hipStream_t stream) {
    const float* Q = (const float*)d_in[0];
    const float* K = (const float*)d_in[1];
    const float* V = (const float*)d_in[2];
    float* O = (float*)d_out;
    dim3 grid(SEQ / QBLK, NH);
    fa_fwd_kernel<<<grid, dim3(256), 0, stream>>>(Q, K, V, O);
}

// Round 7
// 225.730 us; speedup vs baseline: 1.3091x; 1.0802x over previous
//
#include <hip/hip_runtime.h>

#define SEQ   2048
#define NH    32
#define NKV   8
#define HD    128
#define QBLK  128
#define KVBLK 64
#define SCALE 0.08838834764831845f
#define QSTRIDE  4096
#define KVSTRIDE 1024
#define KPAD 136  // K rows: 128 bf16 data + 8 pad = 272B -> b128 reads & b64 writes at bank floor

typedef __attribute__((ext_vector_type(8))) __bf16 bf16x8;
typedef __attribute__((ext_vector_type(4))) __bf16 bf16x4;
typedef __attribute__((ext_vector_type(4))) float  f32x4;

__device__ __forceinline__ unsigned pkbf(float a, float b) {
    union { __bf16 h[2]; unsigned u; } w;
    w.h[0] = (__bf16)a; w.h[1] = (__bf16)b;
    return w.u;
}

// Vt layout: [d][64 k] bf16 rows (128B), swizzled in 8B slots: slot ^= (d ^ (d>>2)) & 15.
// GF(2)-checked: PV b64 reads (d low bits vary per lane) AND transpose b64 writes
// (d high bits vary per lane) both land exactly on the 4-lane/slot bank floor.
__device__ __forceinline__ int vt_swz(int d) { return (d ^ (d >> 2)) & 15; }

__global__ __launch_bounds__(512, 2)
void fa_fwd_kernel(const float* __restrict__ Q, const float* __restrict__ K,
                   const float* __restrict__ V, float* __restrict__ O) {
    __shared__ __bf16 Klds[KVBLK][KPAD];   // [k][d]
    __shared__ __bf16 Vt[HD * 64];         // [d][k], 8B-slot swizzled

    const int h    = blockIdx.y;
    const int qb   = gridDim.x - 1 - blockIdx.x;   // heavy blocks first
    const int hkv  = h >> 2;
    const int tid  = threadIdx.x;
    const int wave = tid >> 6;                     // 0..7: q-rows [q0+16w, +16)
    const int lane = tid & 63;
    const int lmod = lane & 15;
    const int lhi  = lane >> 4;
    const int q0   = qb * QBLK;

    // ---- Q fragments (scaled, bf16): B-frag for swapped QK^T ----
    bf16x8 qfrag[4];
    {
        const float* qp = Q + (size_t)(q0 + wave * 16 + lmod) * QSTRIDE + h * HD;
#pragma unroll
        for (int ks = 0; ks < 4; ++ks) {
            f32x4 a = *(const f32x4*)(qp + ks * 32 + lhi * 8);
            f32x4 b = *(const f32x4*)(qp + ks * 32 + lhi * 8 + 4);
            bf16x8 f;
            f[0] = (__bf16)(a[0] * SCALE); f[1] = (__bf16)(a[1] * SCALE);
            f[2] = (__bf16)(a[2] * SCALE); f[3] = (__bf16)(a[3] * SCALE);
            f[4] = (__bf16)(b[0] * SCALE); f[5] = (__bf16)(b[1] * SCALE);
            f[6] = (__bf16)(b[2] * SCALE); f[7] = (__bf16)(b[3] * SCALE);
            qfrag[ks] = f;
        }
    }

    // ---- staging registers (prefetch in flight across compute); 512 threads ----
    f32x4 kr[4];        // K: 4 rows x float4
    f32x4 vr[4];        // V: 4 k-rows x float4 (one k-quad x d-quad patch)
    const int dq   = tid & 31;        // V: d-quad 0..31 (coalesced)
    const int kg   = tid >> 5;        // V: k-quad 0..15
    const int krow = tid >> 5;        // K: row-within-16
    const int kcol = (tid & 31) * 4;  // K: d column

    auto LOAD_KV = [&](int kv0) {
        const float* kp = K + (size_t)kv0 * KVSTRIDE + hkv * HD + kcol;
#pragma unroll
        for (int i = 0; i < 4; ++i)
            kr[i] = *(const f32x4*)(kp + (size_t)(i * 16 + krow) * KVSTRIDE);
        const float* vp = V + (size_t)(kv0 + kg * 4) * KVSTRIDE + hkv * HD + dq * 4;
#pragma unroll
        for (int rr = 0; rr < 4; ++rr)
            vr[rr] = *(const f32x4*)(vp + rr * KVSTRIDE);
    };

    auto WRITE_KV = [&]() {
#pragma unroll
        for (int i = 0; i < 4; ++i) {
            bf16x4 w = {(__bf16)kr[i][0], (__bf16)kr[i][1], (__bf16)kr[i][2], (__bf16)kr[i][3]};
            *(bf16x4*)&Klds[i * 16 + krow][kcol] = w;
        }
#pragma unroll
        for (int c = 0; c < 4; ++c) {
            const int d = dq * 4 + c;
            bf16x4 w = {(__bf16)vr[0][c], (__bf16)vr[1][c],
                        (__bf16)vr[2][c], (__bf16)vr[3][c]};
            *(bf16x4*)&Vt[d * 64 + ((kg ^ vt_swz(d)) << 2)] = w;
        }
    };

    f32x4 acc[8];   // O^T: acc[dt][r] = O[q=lmod][d = dt*16 + lhi*4 + r]
#pragma unroll
    for (int d = 0; d < 8; ++d) acc[d] = (f32x4){0.f, 0.f, 0.f, 0.f};
    float rmax = -1e30f, rsum = 0.f;   // per-lane state for q = lmod (replicated over lhi)

    LOAD_KV(0);
    WRITE_KV();

    const int nt = 2 * qb + 2;
    const int qg = q0 + wave * 16 + lmod;    // this lane's global q row
    for (int t = 0; t < nt; ++t) {
        __syncthreads();                       // tile t staged & prior reads done
        const bool pf = (t + 1 < nt);
        if (pf) LOAD_KV((t + 1) * KVBLK);      // fire next tile's loads (hidden under compute)

        // waves 0-3: final tile is entirely above the diagonal -> skip compute
        const bool active = !(wave < 4 && t == nt - 1);
        if (active) {
            // ---- swapped QK^T: S^T[k][q], lane holds k = ct*16 + lhi*4 + r, q = lmod ----
            f32x4 s[4];
            __builtin_amdgcn_s_setprio(1);
#pragma unroll
            for (int ct = 0; ct < 4; ++ct) {
                f32x4 c = (f32x4){0.f, 0.f, 0.f, 0.f};
#pragma unroll
                for (int ks = 0; ks < 4; ++ks) {
                    bf16x8 kf = *(const bf16x8*)&Klds[ct * 16 + lmod][ks * 32 + lhi * 8];
                    c = __builtin_amdgcn_mfma_f32_16x16x32_bf16(kf, qfrag[ks], c, 0, 0, 0);
                }
                s[ct] = c;
            }
            __builtin_amdgcn_s_setprio(0);

            if (t >= nt - 2) {                 // diagonal region
                const int kv0 = t * KVBLK;
#pragma unroll
                for (int ct = 0; ct < 4; ++ct)
#pragma unroll
                    for (int r = 0; r < 4; ++r)
                        if (kv0 + ct * 16 + lhi * 4 + r > qg) s[ct][r] = -1e30f;
            }

            // ---- lane-local online softmax ----
            float tmax = s[0][0];
#pragma unroll
            for (int ct = 0; ct < 4; ++ct)
#pragma unroll
                for (int r = 0; r < 4; ++r) tmax = fmaxf(tmax, s[ct][r]);
            tmax = fmaxf(tmax, __shfl_xor(tmax, 16));
            tmax = fmaxf(tmax, __shfl_xor(tmax, 32));
            const float mnew = fmaxf(rmax, tmax);
            const float corr = __expf(rmax - mnew);
            float psum = 0.f;
#pragma unroll
            for (int ct = 0; ct < 4; ++ct)
#pragma unroll
                for (int r = 0; r < 4; ++r) {
                    s[ct][r] = __expf(s[ct][r] - mnew);
                    psum += s[ct][r];
                }
            psum += __shfl_xor(psum, 16);
            psum += __shfl_xor(psum, 32);
            rsum = rsum * corr + psum;
            rmax = mnew;
#pragma unroll
            for (int d = 0; d < 8; ++d) acc[d] *= corr;

            // ---- pack P to bf16 + cross-lane redistribute into PV B-fragments ----
            unsigned pk[4][2];
#pragma unroll
            for (int ct = 0; ct < 4; ++ct) {
                pk[ct][0] = pkbf(s[ct][0], s[ct][1]);
                pk[ct][1] = pkbf(s[ct][2], s[ct][3]);
            }
            const int  sA    = lmod + ((lhi & 1) << 5);
            const int  sB    = sA + 16;
            const bool selhi = (lhi >> 1) != 0;
            bf16x8 pfrag[2];
#pragma unroll
            for (int ks2 = 0; ks2 < 2; ++ks2) {
                const int ctA = ks2 * 2, ctB = ks2 * 2 + 1;
                unsigned d0a = __shfl((int)pk[ctA][0], sA), d0b = __shfl((int)pk[ctB][0], sA);
                unsigned d1a = __shfl((int)pk[ctA][1], sA), d1b = __shfl((int)pk[ctB][1], sA);
                unsigned d2a = __shfl((int)pk[ctA][0], sB), d2b = __shfl((int)pk[ctB][0], sB);
                unsigned d3a = __shfl((int)pk[ctA][1], sB), d3b = __shfl((int)pk[ctB][1], sB);
                union { unsigned u[4]; bf16x8 v; } fb;
                fb.u[0] = selhi ? d0b : d0a;
                fb.u[1] = selhi ? d1b : d1a;
                fb.u[2] = selhi ? d2b : d2a;
                fb.u[3] = selhi ? d3b : d3a;
                pfrag[ks2] = fb.v;
            }

            // ---- swapped PV: O^T += V^T * P^T  (2x b64 swizzled reads per fragment) ----
            __builtin_amdgcn_s_setprio(1);
#pragma unroll
            for (int dt = 0; dt < 8; ++dt) {
                const int d    = dt * 16 + lmod;
                const int rb   = d * 64;
                const int swzd = vt_swz(d);
                f32x4 c = acc[dt];
#pragma unroll
                for (int ks2 = 0; ks2 < 2; ++ks2) {
                    union { bf16x4 h4[2]; bf16x8 v8; } vf;
#pragma unroll
                    for (int hh = 0; hh < 2; ++hh) {
                        const int slot = ((ks2 << 3) | (lhi << 1) | hh) ^ swzd;
                        vf.h4[hh] = *(const bf16x4*)&Vt[rb + slot * 4];
                    }
                    c = __builtin_amdgcn_mfma_f32_16x16x32_bf16(vf.v8, pfrag[ks2], c, 0, 0, 0);
                }
                acc[dt] = c;
            }
            __builtin_amdgcn_s_setprio(0);
        }

        __syncthreads();                       // all reads of tile t done
        if (pf) WRITE_KV();                    // stage tile t+1 (vmcnt waits here, hidden)
    }

    // ---- epilogue: O = O^T/rsum, float4 stores ----
    const float inv = 1.0f / rsum;
    float* op = O + (size_t)qg * QSTRIDE + h * HD + lhi * 4;
#pragma unroll
    for (int dt = 0; dt < 8; ++dt) {
        f32x4 o = acc[dt] * inv;
        *(f32x4*)(op + dt * 16) = o;
    }
}

extern "C" void kernel_launch(void* const* d_in, const int* in_sizes, int n_in,
                              void* d_out, int out_size, void* d_ws, size_t ws_size,
                              hipStream_t stream) {
    const float* Q = (const float*)d_in[0];
    const float* K = (const float*)d_in[1];
    const float* V = (const float*)d_in[2];
    float* O = (float*)d_out;
    dim3 grid(SEQ / QBLK, NH);
    fa_fwd_kernel<<<grid, dim3(512), 0, stream>>>(Q, K, V, O);
}

// Round 10
// 177.781 us; speedup vs baseline: 1.6622x; 1.2697x over previous
//
#include <hip/hip_runtime.h>

#define SEQ   2048
#define NH    32
#define NKV   8
#define HD    128
#define QBLK  64
#define KVBLK 64
#define NQB   (SEQ / QBLK)   // 32 q-blocks, paired (p, 31-p) -> constant 33 tiles/block
#define SCALE 0.08838834764831845f
#define QSTRIDE  4096
#define KVSTRIDE 1024
#define KPAD 136  // K rows: 128 bf16 data + 8 pad = 272B -> b128 reads & b64 writes at bank floor

typedef __attribute__((ext_vector_type(8))) __bf16 bf16x8;
typedef __attribute__((ext_vector_type(4))) __bf16 bf16x4;
typedef __attribute__((ext_vector_type(4))) float  f32x4;

__device__ __forceinline__ unsigned pkbf(float a, float b) {
    union { __bf16 h[2]; unsigned u; } w;
    w.h[0] = (__bf16)a; w.h[1] = (__bf16)b;
    return w.u;
}

// Vt layout: [d][64 k] bf16 rows (128B), swizzled in 8B slots: slot ^= (d ^ (d>>2)) & 15.
// GF(2)-checked: PV b64 reads (d low bits vary) AND transpose b64 writes (d high bits
// vary) both land exactly on the 4-lane/slot bank floor.
__device__ __forceinline__ int vt_swz(int d) { return (d ^ (d >> 2)) & 15; }

__global__ __launch_bounds__(256, 2)
void fa_fwd_kernel(const float* __restrict__ Q, const float* __restrict__ K,
                   const float* __restrict__ V, float* __restrict__ O) {
    __shared__ __bf16 Klds[2][KVBLK][KPAD];   // [buf][k][d]
    __shared__ __bf16 Vt[2][HD * 64];         // [buf][d][k], 8B-slot swizzled

    const int h    = blockIdx.y;
    const int pr   = blockIdx.x;               // pair index 0..15
    const int hkv  = h >> 2;
    const int tid  = threadIdx.x;
    const int wave = tid >> 6;
    const int lane = tid & 63;
    const int lmod = lane & 15;
    const int lhi  = lane >> 4;

    // ---- staging registers (prefetch in flight across compute) ----
    f32x4 kr[8];        // K: 8 rows x float4
    f32x4 vr[2][4];     // V: 2 k-groups x 4 rows x float4
    const int dq    = tid & 31;       // V: d-quad 0..31 (coalesced)
    const int kg2   = tid >> 5;       // V: k-group base 0..7
    const int krow  = tid >> 5;       // K: row-within-8 0..7
    const int kcol  = (tid & 31) * 4; // K: d column

    auto LOAD_KV = [&](int kv0) {
        const float* kp = K + (size_t)kv0 * KVSTRIDE + hkv * HD + kcol;
#pragma unroll
        for (int i = 0; i < 8; ++i)
            kr[i] = *(const f32x4*)(kp + (size_t)(i * 8 + krow) * KVSTRIDE);
#pragma unroll
        for (int it = 0; it < 2; ++it) {
            const int kg = kg2 + it * 8;
            const float* vp = V + (size_t)(kv0 + kg * 4) * KVSTRIDE + hkv * HD + dq * 4;
#pragma unroll
            for (int rr = 0; rr < 4; ++rr)
                vr[it][rr] = *(const f32x4*)(vp + rr * KVSTRIDE);
        }
    };

    auto WRITE_KV = [&](int buf) {
#pragma unroll
        for (int i = 0; i < 8; ++i) {
            bf16x4 w = {(__bf16)kr[i][0], (__bf16)kr[i][1], (__bf16)kr[i][2], (__bf16)kr[i][3]};
            *(bf16x4*)&Klds[buf][i * 8 + krow][kcol] = w;
        }
#pragma unroll
        for (int it = 0; it < 2; ++it) {
            const int kg = kg2 + it * 8;
#pragma unroll
            for (int c = 0; c < 4; ++c) {
                const int d = dq * 4 + c;
                bf16x4 w = {(__bf16)vr[it][0][c], (__bf16)vr[it][1][c],
                            (__bf16)vr[it][2][c], (__bf16)vr[it][3][c]};
                *(bf16x4*)&Vt[buf][d * 64 + ((kg ^ vt_swz(d)) << 2)] = w;
            }
        }
    };

    // ---- prologue: stage tile 0 of segment 0 into buffer 0 ----
    LOAD_KV(0);
    WRITE_KV(0);
    int par = 0;   // LDS buffer parity of the tile about to be computed

    const int qbs[2] = {NQB - 1 - pr, pr};    // heavy segment first
    for (int seg = 0; seg < 2; ++seg) {
        const int qb = qbs[seg];
        const int nt = qb + 1;
        const int q0 = qb * QBLK;
        const int qg = q0 + wave * 16 + lmod;  // this lane's global q row

        // ---- Q fragments (scaled, bf16): B-frag for swapped QK^T ----
        bf16x8 qfrag[4];
        {
            const float* qp = Q + (size_t)qg * QSTRIDE + h * HD;
#pragma unroll
            for (int ks = 0; ks < 4; ++ks) {
                f32x4 a = *(const f32x4*)(qp + ks * 32 + lhi * 8);
                f32x4 b = *(const f32x4*)(qp + ks * 32 + lhi * 8 + 4);
                bf16x8 f;
                f[0] = (__bf16)(a[0] * SCALE); f[1] = (__bf16)(a[1] * SCALE);
                f[2] = (__bf16)(a[2] * SCALE); f[3] = (__bf16)(a[3] * SCALE);
                f[4] = (__bf16)(b[0] * SCALE); f[5] = (__bf16)(b[1] * SCALE);
                f[6] = (__bf16)(b[2] * SCALE); f[7] = (__bf16)(b[3] * SCALE);
                qfrag[ks] = f;
            }
        }

        f32x4 acc[8];   // O^T: acc[dt][r] = O[q=lmod][d = dt*16 + lhi*4 + r]
#pragma unroll
        for (int d = 0; d < 8; ++d) acc[d] = (f32x4){0.f, 0.f, 0.f, 0.f};
        float rmax = -1e30f, rsum = 0.f;

        for (int t = 0; t < nt; ++t) {
            // prefetch: next tile of this segment, or tile 0 of segment 1
            const bool pf = (t + 1 < nt) || (seg == 0);
            if (pf) LOAD_KV((t + 1 < nt) ? (t + 1) * KVBLK : 0);

            __syncthreads();   // buf[par] writes visible; all reads of buf[par^1] retired

            // ---- swapped QK^T: S^T[k][q], lane holds k = ct*16+lhi*4+r, q = lmod ----
            f32x4 s[4];
            __builtin_amdgcn_s_setprio(1);
#pragma unroll
            for (int ct = 0; ct < 4; ++ct) {
                f32x4 c = (f32x4){0.f, 0.f, 0.f, 0.f};
#pragma unroll
                for (int ks = 0; ks < 4; ++ks) {
                    bf16x8 kf = *(const bf16x8*)&Klds[par][ct * 16 + lmod][ks * 32 + lhi * 8];
                    c = __builtin_amdgcn_mfma_f32_16x16x32_bf16(kf, qfrag[ks], c, 0, 0, 0);
                }
                s[ct] = c;
            }
            __builtin_amdgcn_s_setprio(0);

            if (t == nt - 1) {                 // diagonal tile of this segment
                const int kv0 = t * KVBLK;
#pragma unroll
                for (int ct = 0; ct < 4; ++ct)
#pragma unroll
                    for (int r = 0; r < 4; ++r)
                        if (kv0 + ct * 16 + lhi * 4 + r > qg) s[ct][r] = -1e30f;
            }

            // ---- lane-local online softmax ----
            float tmax = s[0][0];
#pragma unroll
            for (int ct = 0; ct < 4; ++ct)
#pragma unroll
                for (int r = 0; r < 4; ++r) tmax = fmaxf(tmax, s[ct][r]);
            tmax = fmaxf(tmax, __shfl_xor(tmax, 16));
            tmax = fmaxf(tmax, __shfl_xor(tmax, 32));
            const float mnew = fmaxf(rmax, tmax);
            const float corr = __expf(rmax - mnew);
            float psum = 0.f;
#pragma unroll
            for (int ct = 0; ct < 4; ++ct)
#pragma unroll
                for (int r = 0; r < 4; ++r) {
                    s[ct][r] = __expf(s[ct][r] - mnew);
                    psum += s[ct][r];
                }
            psum += __shfl_xor(psum, 16);
            psum += __shfl_xor(psum, 32);
            rsum = rsum * corr + psum;
            rmax = mnew;
#pragma unroll
            for (int d = 0; d < 8; ++d) acc[d] *= corr;

            // ---- pack P to bf16 + cross-lane redistribute into PV B-fragments ----
            unsigned pk[4][2];
#pragma unroll
            for (int ct = 0; ct < 4; ++ct) {
                pk[ct][0] = pkbf(s[ct][0], s[ct][1]);
                pk[ct][1] = pkbf(s[ct][2], s[ct][3]);
            }
            const int  sA    = lmod + ((lhi & 1) << 5);
            const int  sB    = sA + 16;
            const bool selhi = (lhi >> 1) != 0;
            bf16x8 pfrag[2];
#pragma unroll
            for (int ks2 = 0; ks2 < 2; ++ks2) {
                const int ctA = ks2 * 2, ctB = ks2 * 2 + 1;
                unsigned d0a = __shfl((int)pk[ctA][0], sA), d0b = __shfl((int)pk[ctB][0], sA);
                unsigned d1a = __shfl((int)pk[ctA][1], sA), d1b = __shfl((int)pk[ctB][1], sA);
                unsigned d2a = __shfl((int)pk[ctA][0], sB), d2b = __shfl((int)pk[ctB][0], sB);
                unsigned d3a = __shfl((int)pk[ctA][1], sB), d3b = __shfl((int)pk[ctB][1], sB);
                union { unsigned u[4]; bf16x8 v; } fb;
                fb.u[0] = selhi ? d0b : d0a;
                fb.u[1] = selhi ? d1b : d1a;
                fb.u[2] = selhi ? d2b : d2a;
                fb.u[3] = selhi ? d3b : d3a;
                pfrag[ks2] = fb.v;
            }

            // ---- swapped PV: O^T += V^T * P^T  (2x b64 swizzled reads per fragment) ----
            __builtin_amdgcn_s_setprio(1);
#pragma unroll
            for (int dt = 0; dt < 8; ++dt) {
                const int d    = dt * 16 + lmod;
                const int rb   = d * 64;
                const int swzd = vt_swz(d);
                f32x4 c = acc[dt];
#pragma unroll
                for (int ks2 = 0; ks2 < 2; ++ks2) {
                    union { bf16x4 h4[2]; bf16x8 v8; } vf;
#pragma unroll
                    for (int hh = 0; hh < 2; ++hh) {
                        const int slot = ((ks2 << 3) | (lhi << 1) | hh) ^ swzd;
                        vf.h4[hh] = *(const bf16x4*)&Vt[par][rb + slot * 4];
                    }
                    c = __builtin_amdgcn_mfma_f32_16x16x32_bf16(vf.v8, pfrag[ks2], c, 0, 0, 0);
                }
                acc[dt] = c;
            }
            __builtin_amdgcn_s_setprio(0);

            // stage next tile into the other buffer (no barrier needed: nobody
            // reads buf[par^1] until the top-of-next-iter barrier)
            if (pf) WRITE_KV(par ^ 1);
            par ^= 1;
        }

        // ---- epilogue: O = O^T/rsum, float4 stores ----
        const float inv = 1.0f / rsum;
        float* op = O + (size_t)qg * QSTRIDE + h * HD + lhi * 4;
#pragma unroll
        for (int dt = 0; dt < 8; ++dt) {
            f32x4 o = acc[dt] * inv;
            *(f32x4*)(op + dt * 16) = o;
        }
    }
}

extern "C" void kernel_launch(void* const* d_in, const int* in_sizes, int n_in,
                              void* d_out, int out_size, void* d_ws, size_t ws_size,
                              hipStream_t stream) {
    const float* Q = (const float*)d_in[0];
    const float* K = (const float*)d_in[1];
    const float* V = (const float*)d_in[2];
    float* O = (float*)d_out;
    dim3 grid(NQB / 2, NH);
    fa_fwd_kernel<<<grid, dim3(256), 0, stream>>>(Q, K, V, O);
}